// Round 8
// baseline (80.521 us; speedup 1.0000x reference)
//
#include <hip/hip_runtime.h>
#include <hip/hip_bf16.h>

#define NQ 10000
#define BATCH 64
#define SEQL 200
#define DKD 128
#define SLOTS 64
#define NTOK (BATCH*SEQL)

typedef __attribute__((ext_vector_type(8))) short bh8;
typedef __attribute__((ext_vector_type(4))) float f32x4;
typedef unsigned short u16;
typedef unsigned int u32;

__device__ __forceinline__ float sigmoidf_(float x){ return 1.0f/(1.0f + __expf(-x)); }
__device__ __forceinline__ float tanhf_(float x){
  float ax = fminf(fabsf(x), 30.0f);
  float t = __expf(-2.0f*ax);
  float r = (1.0f-t)/(1.0f+t);
  return copysignf(r, x);
}
// fp32 -> bf16 round-to-nearest-even (bit pattern)
__device__ __forceinline__ u16 f2b(float x){
  u32 u = __builtin_bit_cast(u32, x);
  u32 r = (u + 0x7FFFu + ((u >> 16) & 1u)) >> 16;
  return (u16)r;
}
// convert 8 consecutive fp32 at s -> bh8
__device__ __forceinline__ bh8 cvt8(const float* s){
  float4 v0 = *(const float4*)s, v1 = *(const float4*)(s + 4);
  bh8 h;
  h[0]=(short)f2b(v0.x); h[1]=(short)f2b(v0.y); h[2]=(short)f2b(v0.z); h[3]=(short)f2b(v0.w);
  h[4]=(short)f2b(v1.x); h[5]=(short)f2b(v1.y); h[6]=(short)f2b(v1.z); h[7]=(short)f2b(v1.w);
  return h;
}
// physical byte offset of logical (row, col16) in a row-major LDS tile,
// G4 XOR swizzle (16-lane stride-row MFMA fragment reads otherwise 16-way conflict)
__device__ __forceinline__ int swz(int row, int col16, int rowBytes){
  return row*rowBytes + ((col16 ^ (row & 7)) << 4);
}

// ---------------- WEA: blocks 0..399 = W (softmax(k Mk^T)); 400..799 = E/A ----------------
// 512 thr = 8 waves; 32 tok/block; MFMA 16x16x32 bf16.
// w written row-major [b][t][s]; e/a written TRANSPOSED [b][d][t].
__global__ __launch_bounds__(512) void wea_kernel(
    const int* __restrict__ qseq, const int* __restrict__ cseq,
    const float* __restrict__ q_emb, const float* __restrict__ v_emb,
    const float* __restrict__ Mk, const float* __restrict__ eW,
    const float* __restrict__ aW,
    const float* __restrict__ eb, const float* __restrict__ ab,
    float* __restrict__ w_out, float* __restrict__ eT, float* __restrict__ aT)
{
  __shared__ __align__(16) char smem[73728];
  char* As = smem;                       // A tile [32 rows][256B]
  char* Bs = smem + 8192;                // W: Mk [64][256B]; EA: [256][256B]
  float* Ls = (float*)(smem + 24576);    // W logits [32][68] f32

  const int tid = threadIdx.x;
  const int l = tid & 63, wv = tid >> 6;
  const bool isW = (blockIdx.x < 400);
  const int tok0 = (isW ? blockIdx.x : blockIdx.x - 400) * 32;

  { // stage A: gather 32 embedding rows, cvt fp32->bf16, swizzled write (1 chunk/thread)
    int row = tid >> 4, c16 = tid & 15;
    const float* src;
    if (isW){ int q = qseq[tok0+row]; src = q_emb + (size_t)q*DKD + c16*8; }
    else    { int x = qseq[tok0+row] + NQ*cseq[tok0+row]; src = v_emb + (size_t)x*DKD + c16*8; }
    *(bh8*)(As + swz(row, c16, 256)) = cvt8(src);
  }
  if (isW){ // stage B = Mk (64 rows x 16 chunks), fp32 -> bf16
    #pragma unroll
    for (int m = 0; m < 2; ++m){
      int idx = tid + 512*m; int row = idx >> 4, c16 = idx & 15;
      *(bh8*)(Bs + swz(row, c16, 256)) = cvt8(Mk + (size_t)row*DKD + c16*8);
    }
  } else {  // stage B = [eW; aW] (256 rows x 16 chunks), fp32 -> bf16
    #pragma unroll
    for (int m = 0; m < 8; ++m){
      int idx = tid + 512*m; int row = idx >> 4, c16 = idx & 15;
      const float* src = (row < 128) ? (eW + (size_t)row*DKD) : (aW + (size_t)(row-128)*DKD);
      *(bh8*)(Bs + swz(row, c16, 256)) = cvt8(src + c16*8);
    }
  }
  __syncthreads();

  if (isW){
    const int m = wv & 1, n = wv >> 1;        // 8 waves -> 8 output tiles
    f32x4 acc = {0.f,0.f,0.f,0.f};
    #pragma unroll
    for (int kc = 0; kc < 4; ++kc){
      bh8 af = *(const bh8*)(As + swz(m*16 + (l&15), kc*4 + (l>>4), 256));
      bh8 bf = *(const bh8*)(Bs + swz(n*16 + (l&15), kc*4 + (l>>4), 256));
      acc = __builtin_amdgcn_mfma_f32_16x16x32_bf16(af, bf, acc, 0, 0, 0);
    }
    #pragma unroll
    for (int r = 0; r < 4; ++r){
      int tok = m*16 + (l>>4)*4 + r, out = n*16 + (l&15);
      Ls[tok*68 + out] = acc[r];
    }
    __syncthreads();
    // softmax: wave wv owns tokens 4wv..4wv+3; lane = slot
    #pragma unroll
    for (int i = 0; i < 4; ++i){
      int tok = wv*4 + i;
      float x = Ls[tok*68 + l];
      float mx = x;
      #pragma unroll
      for (int off = 32; off >= 1; off >>= 1) mx = fmaxf(mx, __shfl_xor(mx, off));
      float p = __expf(x - mx);
      float s = p;
      #pragma unroll
      for (int off = 32; off >= 1; off >>= 1) s += __shfl_xor(s, off);
      w_out[(size_t)(tok0+tok)*SLOTS + l] = p / s;
    }
  } else {
    const int m = wv & 1, nq = (wv >> 1) * 4; // 4 n-tiles per wave
    f32x4 acc[4] = {{0.f,0.f,0.f,0.f},{0.f,0.f,0.f,0.f},{0.f,0.f,0.f,0.f},{0.f,0.f,0.f,0.f}};
    #pragma unroll
    for (int kc = 0; kc < 4; ++kc){
      bh8 af = *(const bh8*)(As + swz(m*16 + (l&15), kc*4 + (l>>4), 256));
      #pragma unroll
      for (int j = 0; j < 4; ++j){
        bh8 bf = *(const bh8*)(Bs + swz((nq+j)*16 + (l&15), kc*4 + (l>>4), 256));
        acc[j] = __builtin_amdgcn_mfma_f32_16x16x32_bf16(af, bf, acc[j], 0, 0, 0);
      }
    }
    // transposed store: 4 acc values = 4 consecutive tokens at fixed d -> one float4
    #pragma unroll
    for (int j = 0; j < 4; ++j){
      int out = (nq+j)*16 + (l&15);
      bool is_e = (out < 128);
      int dd = out & 127;
      float bias = is_e ? eb[dd] : ab[dd];
      f32x4 sv;
      #pragma unroll
      for (int r = 0; r < 4; ++r){
        float xv = acc[j][r] + bias;
        sv[r] = is_e ? sigmoidf_(xv) : tanhf_(xv);
      }
      int tg = tok0 + m*16 + (l>>4)*4;       // first of 4 consecutive tokens
      int bb = tg / SEQL, tl = tg - bb*SEQL;
      float* dst = (is_e ? eT : aT) + ((size_t)bb*DKD + dd)*SEQL + tl;
      *(f32x4*)dst = sv;
    }
  }
}

// ---------------- Scan R8: ONE WAVE PER (b,d) CHAIN; slot = lane. ----------------
// 8192 waves = 8 waves/SIMD (max occupancy) -> latency hidden by TLP, not prefetch.
// Per t: coalesced 256B w load, 1 mul, 6-op DPP full-wave reduce (-> lane 63),
// 2 FMA update, lane-63 bf16 cvt+store. No LDS, no barriers.
__device__ __forceinline__ float wave_sum64(float x){
  float t;
  #define DPPADD(ctrl) \
    t = __builtin_bit_cast(float, __builtin_amdgcn_update_dpp(0, __builtin_bit_cast(int,x), ctrl, 0xf, 0xf, true)); x += t;
  DPPADD(0x111)  // row_shr:1
  DPPADD(0x112)  // row_shr:2
  DPPADD(0x114)  // row_shr:4
  DPPADD(0x118)  // row_shr:8   -> lanes 15/31/47/63 hold row sums
  DPPADD(0x142)  // row_bcast15 -> lane31 = rows01, lane63 = rows23
  DPPADD(0x143)  // row_bcast31 -> lane63 = total
  #undef DPPADD
  return x;  // lane 63 holds the 64-lane sum
}

__global__ __launch_bounds__(256, 8) void scan_kernel(
    const float* __restrict__ Mv0,
    const float* __restrict__ w_in,  // [b][200 t][64 s]
    const float* __restrict__ eT,    // [b][128 d][200 t]
    const float* __restrict__ aT,
    u16* __restrict__ r16)           // [b][200 t][128 d] bf16
{
  const int tid = threadIdx.x;
  const int l  = tid & 63;          // lane = slot s
  const int wv = tid >> 6;
  const int bid = blockIdx.x;
  const int b  = bid & 63;          // same-b blocks share XCD (bid%8 = b%8)
  const int d  = ((bid >> 6) << 2) + wv;   // 0..127
  const bool sl = (l == 63);

  float mv = Mv0[l*DKD + d];        // slot = lane

  const float* wq = w_in + (size_t)b*SEQL*SLOTS + l;
  const float* eq = eT + ((size_t)b*DKD + d)*SEQL;
  const float* aq = aT + ((size_t)b*DKD + d)*SEQL;
  u16* rq = r16 + (size_t)b*SEQL*DKD + d;

  float wa[8], wb[8];

  #define LOADW(W, OFF) { \
    _Pragma("unroll") \
    for (int i = 0; i < 8; ++i) W[i] = wq[((OFF)+i)*SLOTS]; \
    asm volatile("" ::: "memory"); }

  #define CHUNK8(W, OFF) { \
    f32x4 E0 = *(const f32x4*)(eq + (OFF)); \
    f32x4 E1 = *(const f32x4*)(eq + (OFF) + 4); \
    f32x4 A0 = *(const f32x4*)(aq + (OFF)); \
    f32x4 A1 = *(const f32x4*)(aq + (OFF) + 4); \
    _Pragma("unroll") \
    for (int v = 0; v < 8; ++v){ \
      const float ev = (v < 4) ? E0[v] : E1[v-4]; \
      const float av = (v < 4) ? A0[v] : A1[v-4]; \
      float r = W[v] * mv; \
      r = wave_sum64(r); \
      if (sl){ \
        u32 pk; \
        asm volatile("v_cvt_pk_bf16_f32 %0, %1, %2" : "=v"(pk) : "v"(r), "v"(0.f)); \
        rq[v*DKD] = (u16)pk; \
      } \
      mv = fmaf(W[v], fmaf(-mv, ev, av), mv); \
    } \
    rq += 8*DKD; }

  LOADW(wa, 0)
  #pragma unroll 1
  for (int m = 0; m < 12; ++m){
    LOADW(wb, 8)
    CHUNK8(wa, 0)
    LOADW(wa, 16)
    CHUNK8(wb, 8)
    wq += 16*SLOTS; eq += 16; aq += 16;
  }
  CHUNK8(wa, 0)    // chunk 24 (t = 192..199)
  #undef LOADW
  #undef CHUNK8
}

// ---------------- P3: f = tanh([read|k] fW^T + fb); out = sigmoid(f pW + pb) ----------------
// 512 thr = 8 waves; 32 tok/block; A = [r16 | k] bf16 (K=256), B = fW cvt'd. LDS 80 KiB.
__global__ __launch_bounds__(512) void p3_kernel(
    const int* __restrict__ qseq, const float* __restrict__ q_emb,
    const u16* __restrict__ r16, const float* __restrict__ fW,
    const float* __restrict__ fb, const float* __restrict__ pW,
    const float* __restrict__ pb, float* __restrict__ out)
{
  __shared__ __align__(16) char smem[81920];
  char* As = smem;            // [32 rows][512B]
  char* Bs = smem + 16384;    // [128 rows][512B]

  const int tid = threadIdx.x;
  const int l = tid & 63, wv = tid >> 6;
  const int tok0 = blockIdx.x * 32;

  #pragma unroll
  for (int m = 0; m < 2; ++m){   // stage A: 1024 chunks (rows 512B = 32 chunks)
    int idx = tid + 512*m; int row = idx >> 5, c16 = idx & 31;
    bh8 v;
    if (c16 < 16){
      v = *(const bh8*)(r16 + (size_t)(tok0+row)*DKD + c16*8);
    } else {
      int q = qseq[tok0+row];
      v = cvt8(q_emb + (size_t)q*DKD + (c16-16)*8);
    }
    *(bh8*)(As + swz(row, c16, 512)) = v;
  }
  #pragma unroll
  for (int m = 0; m < 8; ++m){   // stage B: 4096 chunks, fp32 fW -> bf16
    int idx = tid + 512*m; int row = idx >> 5, c16 = idx & 31;
    *(bh8*)(Bs + swz(row, c16, 512)) = cvt8(fW + (size_t)row*256 + c16*8);
  }
  __syncthreads();

  const int m = wv & 1, np = (wv >> 1) * 2;   // 2 n-tiles per wave
  f32x4 acc[2] = {{0.f,0.f,0.f,0.f},{0.f,0.f,0.f,0.f}};
  #pragma unroll
  for (int kc = 0; kc < 8; ++kc){
    bh8 af = *(const bh8*)(As + swz(m*16 + (l&15), kc*4 + (l>>4), 512));
    #pragma unroll
    for (int j = 0; j < 2; ++j){
      bh8 bf = *(const bh8*)(Bs + swz((np+j)*16 + (l&15), kc*4 + (l>>4), 512));
      acc[j] = __builtin_amdgcn_mfma_f32_16x16x32_bf16(af, bf, acc[j], 0, 0, 0);
    }
  }
  // per-lane partial p over this wave's 32 out-columns
  float pp[4] = {0.f,0.f,0.f,0.f};
  #pragma unroll
  for (int j = 0; j < 2; ++j){
    int o = (np+j)*16 + (l&15);
    float bias = fb[o], pw = pW[o];
    #pragma unroll
    for (int r = 0; r < 4; ++r){
      float f = tanhf_(acc[j][r] + bias);
      pp[r] = fmaf(f, pw, pp[r]);
    }
  }
  #pragma unroll
  for (int r = 0; r < 4; ++r){   // reduce across the 16 out-lanes
    pp[r] += __shfl_xor(pp[r], 1);
    pp[r] += __shfl_xor(pp[r], 2);
    pp[r] += __shfl_xor(pp[r], 4);
    pp[r] += __shfl_xor(pp[r], 8);
  }
  __syncthreads();
  float* pbuf = (float*)smem;    // overlay on As (done with it): [8 waves][32 tok]
  if ((l & 15) == 0){
    #pragma unroll
    for (int r = 0; r < 4; ++r){
      int tok = m*16 + (l>>4)*4 + r;
      pbuf[wv*32 + tok] = pp[r];
    }
  }
  __syncthreads();
  if (tid < 32){
    int mm = tid >> 4;   // token's m-half -> waves with wv&1 == mm
    float s = pbuf[(mm+0)*32 + tid] + pbuf[(mm+2)*32 + tid]
            + pbuf[(mm+4)*32 + tid] + pbuf[(mm+6)*32 + tid];
    out[tok0 + tid] = sigmoidf_(s + pb[0]);
  }
}

extern "C" void kernel_launch(void* const* d_in, const int* in_sizes, int n_in,
                              void* d_out, int out_size, void* d_ws, size_t ws_size,
                              hipStream_t stream) {
  const int*   qseq  = (const int*)d_in[0];
  const int*   cseq  = (const int*)d_in[1];
  const float* q_emb = (const float*)d_in[2];
  const float* v_emb = (const float*)d_in[3];
  const float* Mk    = (const float*)d_in[4];
  const float* Mv0   = (const float*)d_in[5];
  const float* eW    = (const float*)d_in[6];
  const float* eb    = (const float*)d_in[7];
  const float* aW    = (const float*)d_in[8];
  const float* ab    = (const float*)d_in[9];
  const float* fW    = (const float*)d_in[10];
  const float* fb    = (const float*)d_in[11];
  const float* pW    = (const float*)d_in[12];
  const float* pb    = (const float*)d_in[13];

  char* ws = (char*)d_ws;
  float* w_buf = (float*)ws;                                   // [b][t][s]  3,276,800
  float* eT    = (float*)(ws + 3276800);                       // [b][d][t]  6,553,600
  float* aT    = (float*)(ws + 9830400);                       // [b][d][t]  6,553,600
  u16*   r16   = (u16*)  (ws + 16384000);                      // [b][t][d]  3,276,800 (end ~19.7 MB)
  float* outp  = (float*)d_out;

  hipLaunchKernelGGL(wea_kernel, dim3(800), dim3(512), 0, stream,
                     qseq, cseq, q_emb, v_emb, Mk, eW, aW, eb, ab,
                     w_buf, eT, aT);
  hipLaunchKernelGGL(scan_kernel, dim3(2048), dim3(256), 0, stream,
                     Mv0, w_buf, eT, aT, r16);
  hipLaunchKernelGGL(p3_kernel, dim3(NTOK/32), dim3(512), 0, stream,
                     qseq, q_emb, r16, fW, fb, pW, pb, outp);
}

// Round 9
// 52.482 us; speedup vs baseline: 1.5342x; 1.5342x over previous
//
#include <hip/hip_runtime.h>
#include <hip/hip_bf16.h>

#define NQ 10000
#define BATCH 64
#define SEQL 200
#define DKD 128
#define SLOTS 64
#define NTOK (BATCH*SEQL)

typedef __attribute__((ext_vector_type(8))) short bh8;
typedef __attribute__((ext_vector_type(4))) float f32x4;
typedef unsigned short u16;
typedef unsigned int u32;

__device__ __forceinline__ float sigmoidf_(float x){ return 1.0f/(1.0f + __expf(-x)); }
__device__ __forceinline__ float tanhf_(float x){
  float ax = fminf(fabsf(x), 30.0f);
  float t = __expf(-2.0f*ax);
  float r = (1.0f-t)/(1.0f+t);
  return copysignf(r, x);
}
// fp32 -> bf16 round-to-nearest-even (bit pattern)
__device__ __forceinline__ u16 f2b(float x){
  u32 u = __builtin_bit_cast(u32, x);
  u32 r = (u + 0x7FFFu + ((u >> 16) & 1u)) >> 16;
  return (u16)r;
}
__device__ __forceinline__ float b2f(u16 h){
  return __builtin_bit_cast(float, (u32)h << 16);
}
// convert 8 consecutive fp32 at s -> bh8
__device__ __forceinline__ bh8 cvt8(const float* s){
  float4 v0 = *(const float4*)s, v1 = *(const float4*)(s + 4);
  bh8 h;
  h[0]=(short)f2b(v0.x); h[1]=(short)f2b(v0.y); h[2]=(short)f2b(v0.z); h[3]=(short)f2b(v0.w);
  h[4]=(short)f2b(v1.x); h[5]=(short)f2b(v1.y); h[6]=(short)f2b(v1.z); h[7]=(short)f2b(v1.w);
  return h;
}
// physical byte offset of logical (row, col16) in a row-major LDS tile,
// G4 XOR swizzle (16-lane stride-row MFMA fragment reads otherwise 16-way conflict)
__device__ __forceinline__ int swz(int row, int col16, int rowBytes){
  return row*rowBytes + ((col16 ^ (row & 7)) << 4);
}

// ---------------- WEA: blocks 0..399 = W (softmax(k Mk^T)); 400..799 = E/A ----------------
// 512 thr = 8 waves; 32 tok/block; MFMA 16x16x32 bf16.
// w written row-major [b][t][s] as BF16; e/a written TRANSPOSED [b][d][t] f32.
__global__ __launch_bounds__(512) void wea_kernel(
    const int* __restrict__ qseq, const int* __restrict__ cseq,
    const float* __restrict__ q_emb, const float* __restrict__ v_emb,
    const float* __restrict__ Mk, const float* __restrict__ eW,
    const float* __restrict__ aW,
    const float* __restrict__ eb, const float* __restrict__ ab,
    u16* __restrict__ w16, float* __restrict__ eT, float* __restrict__ aT)
{
  __shared__ __align__(16) char smem[73728];
  char* As = smem;                       // A tile [32 rows][256B]
  char* Bs = smem + 8192;                // W: Mk [64][256B]; EA: [256][256B]
  float* Ls = (float*)(smem + 24576);    // W logits [32][68] f32

  const int tid = threadIdx.x;
  const int l = tid & 63, wv = tid >> 6;
  const bool isW = (blockIdx.x < 400);
  const int tok0 = (isW ? blockIdx.x : blockIdx.x - 400) * 32;

  { // stage A: gather 32 embedding rows, cvt fp32->bf16, swizzled write (1 chunk/thread)
    int row = tid >> 4, c16 = tid & 15;
    const float* src;
    if (isW){ int q = qseq[tok0+row]; src = q_emb + (size_t)q*DKD + c16*8; }
    else    { int x = qseq[tok0+row] + NQ*cseq[tok0+row]; src = v_emb + (size_t)x*DKD + c16*8; }
    *(bh8*)(As + swz(row, c16, 256)) = cvt8(src);
  }
  if (isW){ // stage B = Mk (64 rows x 16 chunks), fp32 -> bf16
    #pragma unroll
    for (int m = 0; m < 2; ++m){
      int idx = tid + 512*m; int row = idx >> 4, c16 = idx & 15;
      *(bh8*)(Bs + swz(row, c16, 256)) = cvt8(Mk + (size_t)row*DKD + c16*8);
    }
  } else {  // stage B = [eW; aW] (256 rows x 16 chunks), fp32 -> bf16
    #pragma unroll
    for (int m = 0; m < 8; ++m){
      int idx = tid + 512*m; int row = idx >> 4, c16 = idx & 15;
      const float* src = (row < 128) ? (eW + (size_t)row*DKD) : (aW + (size_t)(row-128)*DKD);
      *(bh8*)(Bs + swz(row, c16, 256)) = cvt8(src + c16*8);
    }
  }
  __syncthreads();

  if (isW){
    const int m = wv & 1, n = wv >> 1;        // 8 waves -> 8 output tiles
    f32x4 acc = {0.f,0.f,0.f,0.f};
    #pragma unroll
    for (int kc = 0; kc < 4; ++kc){
      bh8 af = *(const bh8*)(As + swz(m*16 + (l&15), kc*4 + (l>>4), 256));
      bh8 bf = *(const bh8*)(Bs + swz(n*16 + (l&15), kc*4 + (l>>4), 256));
      acc = __builtin_amdgcn_mfma_f32_16x16x32_bf16(af, bf, acc, 0, 0, 0);
    }
    #pragma unroll
    for (int r = 0; r < 4; ++r){
      int tok = m*16 + (l>>4)*4 + r, out = n*16 + (l&15);
      Ls[tok*68 + out] = acc[r];
    }
    __syncthreads();
    // softmax: wave wv owns tokens 4wv..4wv+3; lane = slot; bf16 store
    #pragma unroll
    for (int i = 0; i < 4; ++i){
      int tok = wv*4 + i;
      float x = Ls[tok*68 + l];
      float mx = x;
      #pragma unroll
      for (int off = 32; off >= 1; off >>= 1) mx = fmaxf(mx, __shfl_xor(mx, off));
      float p = __expf(x - mx);
      float s = p;
      #pragma unroll
      for (int off = 32; off >= 1; off >>= 1) s += __shfl_xor(s, off);
      w16[(size_t)(tok0+tok)*SLOTS + l] = f2b(p / s);
    }
  } else {
    const int m = wv & 1, nq = (wv >> 1) * 4; // 4 n-tiles per wave
    f32x4 acc[4] = {{0.f,0.f,0.f,0.f},{0.f,0.f,0.f,0.f},{0.f,0.f,0.f,0.f},{0.f,0.f,0.f,0.f}};
    #pragma unroll
    for (int kc = 0; kc < 4; ++kc){
      bh8 af = *(const bh8*)(As + swz(m*16 + (l&15), kc*4 + (l>>4), 256));
      #pragma unroll
      for (int j = 0; j < 4; ++j){
        bh8 bf = *(const bh8*)(Bs + swz((nq+j)*16 + (l&15), kc*4 + (l>>4), 256));
        acc[j] = __builtin_amdgcn_mfma_f32_16x16x32_bf16(af, bf, acc[j], 0, 0, 0);
      }
    }
    // transposed store: 4 acc values = 4 consecutive tokens at fixed d -> one float4
    #pragma unroll
    for (int j = 0; j < 4; ++j){
      int out = (nq+j)*16 + (l&15);
      bool is_e = (out < 128);
      int dd = out & 127;
      float bias = is_e ? eb[dd] : ab[dd];
      f32x4 sv;
      #pragma unroll
      for (int r = 0; r < 4; ++r){
        float xv = acc[j][r] + bias;
        sv[r] = is_e ? sigmoidf_(xv) : tanhf_(xv);
      }
      int tg = tok0 + m*16 + (l>>4)*4;       // first of 4 consecutive tokens
      int bb = tg / SEQL, tl = tg - bb*SEQL;
      float* dst = (is_e ? eT : aT) + ((size_t)bb*DKD + dd)*SEQL + tl;
      *(f32x4*)dst = sv;
    }
  }
}

// ---------------- Scan R9: ALL operands in LDS (one barrier), 16-lane chains, ----------------
// barrier-free chunk loop of pure LDS+VALU. Block = (b, 16 d); 512 blocks x 256 thr.
__device__ __forceinline__ float dpp_row_sum16(float x){
  float t;
  t = __builtin_bit_cast(float, __builtin_amdgcn_update_dpp(0, __builtin_bit_cast(int,x), 0x111, 0xf, 0xf, true)); x += t; // row_shr:1
  t = __builtin_bit_cast(float, __builtin_amdgcn_update_dpp(0, __builtin_bit_cast(int,x), 0x112, 0xf, 0xf, true)); x += t; // row_shr:2
  t = __builtin_bit_cast(float, __builtin_amdgcn_update_dpp(0, __builtin_bit_cast(int,x), 0x114, 0xf, 0xf, true)); x += t; // row_shr:4
  t = __builtin_bit_cast(float, __builtin_amdgcn_update_dpp(0, __builtin_bit_cast(int,x), 0x118, 0xf, 0xf, true)); x += t; // row_shr:8
  return x;  // lane 15 (mod 16) holds the 16-lane sum
}

__global__ __launch_bounds__(256) void scan_kernel(
    const float* __restrict__ Mv0,
    const u16* __restrict__ w16,   // [b][200 t][64 s] bf16
    const float* __restrict__ eT,  // [b][128 d][200 t] f32
    const float* __restrict__ aT,
    u16* __restrict__ r16)         // [b][200 t][128 d] bf16
{
  __shared__ float wS[200][68];    // 54,400 B (pad 68: read banks 2-way-free)
  __shared__ float eS[16][204];    // 13,056 B
  __shared__ float aS[16][204];    // 13,056 B   total 80,512 B -> 2 blocks/CU
  const int tid = threadIdx.x;
  const int bid = blockIdx.x;
  const int b   = bid & 63;        // same-b blocks share XCD (bid%8 = b%8)
  const int d0  = (bid >> 6) << 4;
  const int c   = tid >> 4;        // chain: d = d0 + c
  const int g   = tid & 15;        // slot quad: slots 4g..4g+3
  const int d   = d0 + c;
  const bool wl = (g == 15);

  // ---- stage w: 1600 x 16B bf16 chunks -> f32 LDS. t-fast mapping => 2-way-free writes.
  #pragma unroll
  for (int m = 0; m < 7; ++m){
    int i = tid + 256*m;
    if (i < 1600){
      int t8 = i & 7, blk = i >> 3;          // blk = t-block(25) * 8 + c8? No:
      // mapping: i = blk*8 + t8 with blk = (tblk*8 + c8) would re-derive; use direct:
      // t = (i>>3) ... we need t fast within a lane-octet: i = (c8*25 + tblk)*8 + t8
      int c8 = i / 200;                      // 0..7  (column-octet)
      int tt = i - c8*200;                   // 0..199 (t, fast within c8)
      const u16* src = w16 + (size_t)b*SEQL*SLOTS + (size_t)tt*SLOTS + c8*8;
      bh8 v = *(const bh8*)src;
      float f[8];
      #pragma unroll
      for (int j = 0; j < 8; ++j) f[j] = b2f((u16)v[j]);
      *(float4*)&wS[tt][c8*8]     = *(const float4*)&f[0];
      *(float4*)&wS[tt][c8*8 + 4] = *(const float4*)&f[4];
    }
  }
  // ---- stage e/a: 1600 float4, coalesced along t
  #pragma unroll
  for (int m = 0; m < 7; ++m){
    int i = tid + 256*m;
    if (i < 1600){
      int arr = (i >= 800);
      int j = arr ? i - 800 : i;
      int row = j / 50, col = j - row*50;
      const float* src = (arr ? aT : eT) + ((size_t)b*DKD + d0 + row)*SEQL + col*4;
      float4 v = *(const float4*)src;
      float* dst = (arr ? &aS[0][0] : &eS[0][0]) + row*204 + col*4;
      *(float4*)dst = v;
    }
  }

  float mv0 = Mv0[(4*g+0)*DKD + d];
  float mv1 = Mv0[(4*g+1)*DKD + d];
  float mv2 = Mv0[(4*g+2)*DKD + d];
  float mv3 = Mv0[(4*g+3)*DKD + d];
  u16* rq = r16 + (size_t)b*SEQL*DKD + d;

  __syncthreads();                 // the ONLY barrier

  for (int ck = 0; ck < 25; ++ck){
    const int t0 = ck*8;
    #pragma unroll
    for (int u = 0; u < 2; ++u){
      float eq[4], aq[4];
      *(float4*)eq = *(const float4*)&eS[c][t0 + u*4];
      *(float4*)aq = *(const float4*)&aS[c][t0 + u*4];
      #pragma unroll
      for (int v = 0; v < 4; ++v){
        const int tt = t0 + u*4 + v;
        float4 wq = *(const float4*)&wS[tt][4*g];
        float r = wq.x*mv0; r = fmaf(wq.y, mv1, r);
        r = fmaf(wq.z, mv2, r); r = fmaf(wq.w, mv3, r);
        r = dpp_row_sum16(r);
        if (wl) rq[(size_t)tt*DKD] = f2b(r);
        const float ev = eq[v], av = aq[v];
        mv0 = fmaf(wq.x, fmaf(-mv0, ev, av), mv0);
        mv1 = fmaf(wq.y, fmaf(-mv1, ev, av), mv1);
        mv2 = fmaf(wq.z, fmaf(-mv2, ev, av), mv2);
        mv3 = fmaf(wq.w, fmaf(-mv3, ev, av), mv3);
      }
    }
  }
}

// ---------------- P3: f = tanh([read|k] fW^T + fb); out = sigmoid(f pW + pb) ----------------
// 512 thr = 8 waves; 32 tok/block; A = [r16 | k] bf16 (K=256), B = fW cvt'd. LDS 80 KiB.
__global__ __launch_bounds__(512) void p3_kernel(
    const int* __restrict__ qseq, const float* __restrict__ q_emb,
    const u16* __restrict__ r16, const float* __restrict__ fW,
    const float* __restrict__ fb, const float* __restrict__ pW,
    const float* __restrict__ pb, float* __restrict__ out)
{
  __shared__ __align__(16) char smem[81920];
  char* As = smem;            // [32 rows][512B]
  char* Bs = smem + 16384;    // [128 rows][512B]

  const int tid = threadIdx.x;
  const int l = tid & 63, wv = tid >> 6;
  const int tok0 = blockIdx.x * 32;

  #pragma unroll
  for (int m = 0; m < 2; ++m){   // stage A: 1024 chunks (rows 512B = 32 chunks)
    int idx = tid + 512*m; int row = idx >> 5, c16 = idx & 31;
    bh8 v;
    if (c16 < 16){
      v = *(const bh8*)(r16 + (size_t)(tok0+row)*DKD + c16*8);
    } else {
      int q = qseq[tok0+row];
      v = cvt8(q_emb + (size_t)q*DKD + (c16-16)*8);
    }
    *(bh8*)(As + swz(row, c16, 512)) = v;
  }
  #pragma unroll
  for (int m = 0; m < 8; ++m){   // stage B: 4096 chunks, fp32 fW -> bf16
    int idx = tid + 512*m; int row = idx >> 5, c16 = idx & 31;
    *(bh8*)(Bs + swz(row, c16, 512)) = cvt8(fW + (size_t)row*256 + c16*8);
  }
  __syncthreads();

  const int m = wv & 1, np = (wv >> 1) * 2;   // 2 n-tiles per wave
  f32x4 acc[2] = {{0.f,0.f,0.f,0.f},{0.f,0.f,0.f,0.f}};
  #pragma unroll
  for (int kc = 0; kc < 8; ++kc){
    bh8 af = *(const bh8*)(As + swz(m*16 + (l&15), kc*4 + (l>>4), 512));
    #pragma unroll
    for (int j = 0; j < 2; ++j){
      bh8 bf = *(const bh8*)(Bs + swz((np+j)*16 + (l&15), kc*4 + (l>>4), 512));
      acc[j] = __builtin_amdgcn_mfma_f32_16x16x32_bf16(af, bf, acc[j], 0, 0, 0);
    }
  }
  // per-lane partial p over this wave's 32 out-columns
  float pp[4] = {0.f,0.f,0.f,0.f};
  #pragma unroll
  for (int j = 0; j < 2; ++j){
    int o = (np+j)*16 + (l&15);
    float bias = fb[o], pw = pW[o];
    #pragma unroll
    for (int r = 0; r < 4; ++r){
      float f = tanhf_(acc[j][r] + bias);
      pp[r] = fmaf(f, pw, pp[r]);
    }
  }
  #pragma unroll
  for (int r = 0; r < 4; ++r){   // reduce across the 16 out-lanes
    pp[r] += __shfl_xor(pp[r], 1);
    pp[r] += __shfl_xor(pp[r], 2);
    pp[r] += __shfl_xor(pp[r], 4);
    pp[r] += __shfl_xor(pp[r], 8);
  }
  __syncthreads();
  float* pbuf = (float*)smem;    // overlay on As (done with it): [8 waves][32 tok]
  if ((l & 15) == 0){
    #pragma unroll
    for (int r = 0; r < 4; ++r){
      int tok = m*16 + (l>>4)*4 + r;
      pbuf[wv*32 + tok] = pp[r];
    }
  }
  __syncthreads();
  if (tid < 32){
    int mm = tid >> 4;   // token's m-half -> waves with wv&1 == mm
    float s = pbuf[(mm+0)*32 + tid] + pbuf[(mm+2)*32 + tid]
            + pbuf[(mm+4)*32 + tid] + pbuf[(mm+6)*32 + tid];
    out[tok0 + tid] = sigmoidf_(s + pb[0]);
  }
}

extern "C" void kernel_launch(void* const* d_in, const int* in_sizes, int n_in,
                              void* d_out, int out_size, void* d_ws, size_t ws_size,
                              hipStream_t stream) {
  const int*   qseq  = (const int*)d_in[0];
  const int*   cseq  = (const int*)d_in[1];
  const float* q_emb = (const float*)d_in[2];
  const float* v_emb = (const float*)d_in[3];
  const float* Mk    = (const float*)d_in[4];
  const float* Mv0   = (const float*)d_in[5];
  const float* eW    = (const float*)d_in[6];
  const float* eb    = (const float*)d_in[7];
  const float* aW    = (const float*)d_in[8];
  const float* ab    = (const float*)d_in[9];
  const float* fW    = (const float*)d_in[10];
  const float* fb    = (const float*)d_in[11];
  const float* pW    = (const float*)d_in[12];
  const float* pb    = (const float*)d_in[13];

  char* ws = (char*)d_ws;
  u16*   w16   = (u16*)ws;                                     // [b][t][s] bf16  1,638,400
  float* eT    = (float*)(ws + 3276800);                       // [b][d][t]  6,553,600
  float* aT    = (float*)(ws + 9830400);                       // [b][d][t]  6,553,600
  u16*   r16   = (u16*)  (ws + 16384000);                      // [b][t][d]  3,276,800 (end ~19.7 MB)
  float* outp  = (float*)d_out;

  hipLaunchKernelGGL(wea_kernel, dim3(800), dim3(512), 0, stream,
                     qseq, cseq, q_emb, v_emb, Mk, eW, aW, eb, ab,
                     w16, eT, aT);
  hipLaunchKernelGGL(scan_kernel, dim3(512), dim3(256), 0, stream,
                     Mv0, w16, eT, aT, r16);
  hipLaunchKernelGGL(p3_kernel, dim3(NTOK/32), dim3(512), 0, stream,
                     qseq, q_emb, r16, fW, fb, pW, pb, outp);
}